// Round 5
// baseline (317.702 us; speedup 1.0000x reference)
//
#include <hip/hip_runtime.h>
#include <stdint.h>

// SimCLR clear loss, MI355X — round 5: two dispatches total.
// prep: per-segment label sort + fp32->f16 cast + tile table (block 0).
// gemm: upper-triangle 64x64 class tiles, BK=128 (4 K-iters), pos fold on
//       trailing blocks, logdenom folded into the last-arriving block.

#define NROWS 8192
#define DIM   512
#define NCLS  7
#define GEMM_GRID 2048
#define POSB0 1920

typedef _Float16 f16x8 __attribute__((ext_vector_type(8)));
typedef _Float16 f16x4 __attribute__((ext_vector_type(4)));
typedef float    f32x4 __attribute__((ext_vector_type(4)));

__device__ __forceinline__ void load16_g2l(void* lds, const void* g) {
    auto* l3 = reinterpret_cast<__attribute__((address_space(3))) uint32_t*>(
        reinterpret_cast<uintptr_t>(lds));
    auto* g1 = reinterpret_cast<const __attribute__((address_space(1))) uint32_t*>(
        reinterpret_cast<uintptr_t>(g));
    __builtin_amdgcn_global_load_lds(g1, l3, 16, 0, 0);
}

// ---------------- 1. prep: sort-by-label + cast + plan (block 0) ----------------
// One block per 64-row segment. Each block recomputes the global histogram and
// the per-class count of rows before its segment (32 KB label read from L2),
// so no inter-block communication is needed.
__global__ __launch_bounds__(256) void prep_kernel(const float* __restrict__ x,
                                                   const int* __restrict__ labels,
                                                   _Float16* __restrict__ y,
                                                   float* __restrict__ denomS,
                                                   int4* __restrict__ tiles,
                                                   int* __restrict__ nTiles,
                                                   int* __restrict__ counter,
                                                   float* __restrict__ loss) {
    const int tid  = threadIdx.x;
    const int lane = tid & 63;
    const int wv   = tid >> 6;
    const int seg  = blockIdx.x;        // 0..127
    const int segbase = seg * 64;

    // per-thread class counts: total, and "before my segment"
    int cb[NCLS] = {}, ct[NCLS] = {};
    for (int j = 0; j < 32; ++j) {
        int r = tid + j * 256;
        int l = labels[r];
        int before = (r < segbase);
        #pragma unroll
        for (int c = 0; c < NCLS; ++c) {
            int isc = (l == c);
            ct[c] += isc;
            cb[c] += isc & before;
        }
    }
    #pragma unroll
    for (int c = 0; c < NCLS; ++c)
        for (int d = 1; d < 64; d <<= 1) {
            cb[c] += __shfl_xor(cb[c], d, 64);
            ct[c] += __shfl_xor(ct[c], d, 64);
        }
    __shared__ int scb[4][NCLS], sct[4][NCLS];
    __shared__ int wbase[NCLS], soff[NCLS], shist[NCLS];
    if (lane == 0)
        #pragma unroll
        for (int c = 0; c < NCLS; ++c) { scb[wv][c] = cb[c]; sct[wv][c] = ct[c]; }
    __syncthreads();
    if (tid == 0) {
        int o = 0;
        for (int c = 0; c < NCLS; ++c) {
            int tot = sct[0][c] + sct[1][c] + sct[2][c] + sct[3][c];
            int bef = scb[0][c] + scb[1][c] + scb[2][c] + scb[3][c];
            shist[c] = tot; soff[c] = o; wbase[c] = o + bef; o += tot;
        }
    }
    __syncthreads();

    // within-segment rank via ballot (all 4 waves compute identical masks)
    const int lab = labels[segbase + lane];
    unsigned long long m0 = __ballot(lab == 0), m1 = __ballot(lab == 1),
                       m2 = __ballot(lab == 2), m3 = __ballot(lab == 3),
                       m4 = __ballot(lab == 4), m5 = __ballot(lab == 5),
                       m6 = __ballot(lab == 6);
    unsigned long long mym =
        lab == 0 ? m0 : lab == 1 ? m1 : lab == 2 ? m2 : lab == 3 ? m3 :
        lab == 4 ? m4 : lab == 5 ? m5 : m6;
    const unsigned long long lt = (1ull << lane) - 1ull;
    const int dest_lane = wbase[lab] + __builtin_popcountll(mym & lt);

    // copy+cast 16 rows per wave
    #pragma unroll 4
    for (int i = 0; i < 16; ++i) {
        int j = wv * 16 + i;
        int dest = __shfl(dest_lane, j, 64);
        const float4* src = (const float4*)(x + (size_t)(segbase + j) * DIM);
        _Float16* dst = y + (size_t)dest * DIM;
        #pragma unroll
        for (int p = 0; p < 2; ++p) {
            float4 v = src[lane + p * 64];
            f16x4 h;
            h[0] = (_Float16)v.x; h[1] = (_Float16)v.y;
            h[2] = (_Float16)v.z; h[3] = (_Float16)v.w;
            *(f16x4*)(dst + (lane + p * 64) * 4) = h;
        }
    }

    if (tid < 64) denomS[segbase + tid] = 0.f;

    // block 0: tile table + nTiles + counters (it already holds the histogram)
    if (seg == 0) {
        if (tid == 0) { *loss = 0.f; *counter = 0; }
        __shared__ int tb[NCLS + 1];
        if (tid == 0) {
            int t = 0;
            for (int c = 0; c < NCLS; ++c) {
                tb[c] = t;
                int T = (shist[c] + 63) >> 6;
                t += T * (T + 1) / 2;
            }
            tb[NCLS] = t; *nTiles = t;
        }
        __syncthreads();
        const int tot = tb[NCLS];
        for (int t = tid; t < tot; t += 256) {
            int c = 0;
            while (t >= tb[c + 1]) ++c;
            int rem = t - tb[c];
            int T = (shist[c] + 63) >> 6;
            int ti = 0;
            while (rem >= T - ti) { rem -= (T - ti); ++ti; }   // ti<=tj
            int tj = ti + rem;
            tiles[t] = make_int4(soff[c] + ti * 64, soff[c] + tj * 64,
                                 soff[c] + shist[c], 0);
        }
    }
}

// ---------------- 2. gemm + epilogue + pos + last-block logdenom ----------------
// 64x64 tile, BK=128 (4 K-iters -> half the barrier drains), 4 waves each a
// 32x32 quadrant. LDS fragment-ordered [4][4][64][8] per tile; off-diag tiles
// emit row- AND col-sums (S^T reuse); diag tiles stage A only, mask i!=j.
__global__ __launch_bounds__(256, 5) void gemm_denom_kernel(const _Float16* __restrict__ X,
                                                            const int4* __restrict__ tiles,
                                                            const int* __restrict__ nTiles,
                                                            float* __restrict__ denom,
                                                            const float* __restrict__ o1,
                                                            const float* __restrict__ o2,
                                                            int* __restrict__ counter,
                                                            float* __restrict__ loss) {
    __shared__ __align__(16) _Float16 Atile[8192];  // [4][4][64][8] = 16 KiB
    __shared__ __align__(16) _Float16 Btile[8192];
    // post-loop scratch aliases Atile (keeps LDS at exactly 32 KiB -> 5 blocks/CU)
    float* red = (float*)Atile;
    __shared__ int lastFlag;

    const int tid  = threadIdx.x;
    const int lane = tid & 63;
    const int wv   = tid >> 6;
    const int lc   = lane & 15;
    const int lq   = lane >> 4;
    const int l8   = lq * 8;
    const int nT   = *nTiles;

    for (int t = blockIdx.x; t < nT; t += gridDim.x) {
        const int4 d = tiles[t];
        const int bm = d.x, bn = d.y, end = d.z;
        const bool diag = (bm == bn);

        f32x4 acc[2][2] = {};

        for (int kb = 0; kb < DIM; kb += 128) {
            __syncthreads();
            #pragma unroll
            for (int g = 0; g < 8; ++g) {
                int grp = wv + g * 4;             // 0..31, wave-uniform
                if (diag && grp >= 16) continue;  // diag: A tile only
                int idx = grp & 15;
                int kk2 = idx >> 2;               // 0..3 (k-chunk of 32)
                int rg  = idx & 3;                // row group of 16
                int row = (grp < 16 ? bm : bn) + rg * 16 + lc;
                row = min(row, end - 1);          // partial: dup last row, masked later
                int kcol = kb + kk2 * 32 + l8;
                const _Float16* src = X + (size_t)row * DIM + kcol;
                _Float16* dst = (grp < 16 ? Atile : Btile) + ((kk2 * 4 + rg) * 64 + lane) * 8;
                load16_g2l(dst, src);
            }
            __syncthreads();

            const _Float16* Bbase = diag ? Atile : Btile;
            const int rga = (wv >> 1) * 2;
            const int rgb = (wv & 1) * 2;
            #pragma unroll
            for (int kk2 = 0; kk2 < 4; ++kk2) {
                f16x8 af[2], bf[2];
                #pragma unroll
                for (int q = 0; q < 2; ++q)
                    af[q] = *(const f16x8*)&Atile[((kk2 * 4 + rga + q) * 64 + lane) * 8];
                #pragma unroll
                for (int q = 0; q < 2; ++q)
                    bf[q] = *(const f16x8*)&Bbase[((kk2 * 4 + rgb + q) * 64 + lane) * 8];
                #pragma unroll
                for (int mt = 0; mt < 2; ++mt)
                    #pragma unroll
                    for (int nt = 0; nt < 2; ++nt)
                        acc[mt][nt] = __builtin_amdgcn_mfma_f32_16x16x32_f16(
                            af[mt], bf[nt], acc[mt][nt], 0, 0, 0);
            }
        }

        // epilogue. C/D: col = lane&15, row = (lane>>4)*4 + reg   [m89/m91]
        const int row0 = bm + (wv >> 1) * 32;
        const int col0 = bn + (wv & 1) * 32;
        const float cs = 2.0f * 1.4426950408889634f;  // (1/T)*log2(e)

        float colsum[2] = {0.f, 0.f};
        #pragma unroll
        for (int mt = 0; mt < 2; ++mt) {
            #pragma unroll
            for (int r = 0; r < 4; ++r) {
                int grow = row0 + mt * 16 + lq * 4 + r;
                float s = 0.f;
                #pragma unroll
                for (int nt = 0; nt < 2; ++nt) {
                    int gcol = col0 + nt * 16 + lc;
                    float e = exp2f(acc[mt][nt][r] * cs);
                    bool ok = (gcol < end) && (!diag || (grow != gcol));
                    e = ok ? e : 0.f;
                    s += e;
                    colsum[nt] += e;
                }
                #pragma unroll
                for (int dd = 1; dd < 16; dd <<= 1) s += __shfl_xor(s, dd, 64);
                if (lc == 0 && grow < end) atomicAdd(&denom[grow], s);
            }
        }
        if (!diag) {  // mirrored tile rows (off-diag row blocks are always full)
            #pragma unroll
            for (int nt = 0; nt < 2; ++nt) {
                float c2 = colsum[nt];
                c2 += __shfl_xor(c2, 16, 64);
                c2 += __shfl_xor(c2, 32, 64);
                int gcol = col0 + nt * 16 + lc;
                if (lq == 0 && gcol < end) atomicAdd(&denom[gcol], c2);
            }
        }
    }

    __syncthreads();  // all waves past tile loop before Atile is reused as scratch

    // ---- pos fold on trailing blocks ----
    if (blockIdx.x >= POSB0) {
        const int wave = (blockIdx.x - POSB0) * 4 + wv;  // 0..511
        float s = 0.f;
        for (int r = wave; r < 4096; r += 512) {
            const float4* a = (const float4*)(o1 + (size_t)r * DIM);
            const float4* b = (const float4*)(o2 + (size_t)r * DIM);
            float4 va = a[lane], vb = b[lane];
            s += va.x * vb.x + va.y * vb.y + va.z * vb.z + va.w * vb.w;
            va = a[lane + 64]; vb = b[lane + 64];
            s += va.x * vb.x + va.y * vb.y + va.z * vb.z + va.w * vb.w;
        }
        #pragma unroll
        for (int dd = 1; dd < 64; dd <<= 1) s += __shfl_xor(s, dd, 64);
        if (lane == 0) red[wv] = s;
        __syncthreads();
        if (tid == 0)
            atomicAdd(loss, -(red[0] + red[1] + red[2] + red[3]) * (1.0f / 2048.0f));
    }

    // ---- last-arriving block computes mean(log denom) ----
    __threadfence();                       // release: my denom atomics visible
    if (tid == 0) {
        int old = atomicAdd(counter, 1);
        lastFlag = (old == (int)gridDim.x - 1);
    }
    __syncthreads();
    if (lastFlag) {
        __threadfence();                   // acquire
        float v = 0.f;
        for (int i = tid; i < NROWS; i += 256) v += __logf(denom[i]);
        #pragma unroll
        for (int dd = 1; dd < 64; dd <<= 1) v += __shfl_xor(v, dd, 64);
        __syncthreads();                   // red[] free (pos fold done)
        if (lane == 0) red[wv] = v;
        __syncthreads();
        if (tid == 0)
            atomicAdd(loss, (red[0] + red[1] + red[2] + red[3]) * (1.0f / 8192.0f));
    }
}

extern "C" void kernel_launch(void* const* d_in, const int* in_sizes, int n_in,
                              void* d_out, int out_size, void* d_ws, size_t ws_size,
                              hipStream_t stream) {
    const float* out_full = (const float*)d_in[0];  // [8192, 512]
    const float* out_1    = (const float*)d_in[1];  // [4096, 512]
    const float* out_2    = (const float*)d_in[2];  // [4096, 512]
    const int*   labels   = (const int*)d_in[3];    // [8192]
    float* loss = (float*)d_out;

    char* ws = (char*)d_ws;
    _Float16* Xs     = (_Float16*)ws;                 // 8 MiB
    float*    denomS = (float*)(ws + 8388608);        // 32 KiB
    int*      nTiles = (int*)(ws + 8421376);          // 4 B
    int*      counter= (int*)(ws + 8421440);          // 4 B
    int4*     tiles  = (int4*)(ws + 8421504);         // <=33 KiB

    prep_kernel<<<128, 256, 0, stream>>>(out_full, labels, Xs, denomS,
                                         tiles, nTiles, counter, loss);
    gemm_denom_kernel<<<GEMM_GRID, 256, 0, stream>>>(Xs, tiles, nTiles, denomS,
                                                     out_1, out_2, counter, loss);
}

// Round 6
// 124.400 us; speedup vs baseline: 2.5539x; 2.5539x over previous
//
#include <hip/hip_runtime.h>
#include <stdint.h>

// SimCLR clear loss, MI355X — round 6: three dispatches.
// prep: per-segment label sort + fp32->f16 cast + tile table (block 0).
// gemm: upper-triangle 64x64 class tiles, BK=128, pos fold on trailing blocks.
// logdenom: separate kernel (kernel boundary = coherence point — round 5's
//           in-kernel device fences flushed L2 2048x and cost ~200 us).

#define NROWS 8192
#define DIM   512
#define NCLS  7
#define GEMM_GRID 2048
#define POSB0 1920

typedef _Float16 f16x8 __attribute__((ext_vector_type(8)));
typedef _Float16 f16x4 __attribute__((ext_vector_type(4)));
typedef float    f32x4 __attribute__((ext_vector_type(4)));

__device__ __forceinline__ void load16_g2l(void* lds, const void* g) {
    auto* l3 = reinterpret_cast<__attribute__((address_space(3))) uint32_t*>(
        reinterpret_cast<uintptr_t>(lds));
    auto* g1 = reinterpret_cast<const __attribute__((address_space(1))) uint32_t*>(
        reinterpret_cast<uintptr_t>(g));
    __builtin_amdgcn_global_load_lds(g1, l3, 16, 0, 0);
}

// ---------------- 1. prep: sort-by-label + cast + plan (block 0) ----------------
__global__ __launch_bounds__(256) void prep_kernel(const float* __restrict__ x,
                                                   const int* __restrict__ labels,
                                                   _Float16* __restrict__ y,
                                                   float* __restrict__ denomS,
                                                   int4* __restrict__ tiles,
                                                   int* __restrict__ nTiles,
                                                   float* __restrict__ loss) {
    const int tid  = threadIdx.x;
    const int lane = tid & 63;
    const int wv   = tid >> 6;
    const int seg  = blockIdx.x;        // 0..127
    const int segbase = seg * 64;

    // per-thread class counts: total, and "before my segment"
    int cb[NCLS] = {}, ct[NCLS] = {};
    for (int j = 0; j < 32; ++j) {
        int r = tid + j * 256;
        int l = labels[r];
        int before = (r < segbase);
        #pragma unroll
        for (int c = 0; c < NCLS; ++c) {
            int isc = (l == c);
            ct[c] += isc;
            cb[c] += isc & before;
        }
    }
    #pragma unroll
    for (int c = 0; c < NCLS; ++c)
        for (int d = 1; d < 64; d <<= 1) {
            cb[c] += __shfl_xor(cb[c], d, 64);
            ct[c] += __shfl_xor(ct[c], d, 64);
        }
    __shared__ int scb[4][NCLS], sct[4][NCLS];
    __shared__ int wbase[NCLS], soff[NCLS], shist[NCLS];
    if (lane == 0)
        #pragma unroll
        for (int c = 0; c < NCLS; ++c) { scb[wv][c] = cb[c]; sct[wv][c] = ct[c]; }
    __syncthreads();
    if (tid == 0) {
        int o = 0;
        for (int c = 0; c < NCLS; ++c) {
            int tot = sct[0][c] + sct[1][c] + sct[2][c] + sct[3][c];
            int bef = scb[0][c] + scb[1][c] + scb[2][c] + scb[3][c];
            shist[c] = tot; soff[c] = o; wbase[c] = o + bef; o += tot;
        }
    }
    __syncthreads();

    // within-segment rank via ballot (all 4 waves compute identical masks)
    const int lab = labels[segbase + lane];
    unsigned long long m0 = __ballot(lab == 0), m1 = __ballot(lab == 1),
                       m2 = __ballot(lab == 2), m3 = __ballot(lab == 3),
                       m4 = __ballot(lab == 4), m5 = __ballot(lab == 5),
                       m6 = __ballot(lab == 6);
    unsigned long long mym =
        lab == 0 ? m0 : lab == 1 ? m1 : lab == 2 ? m2 : lab == 3 ? m3 :
        lab == 4 ? m4 : lab == 5 ? m5 : m6;
    const unsigned long long lt = (1ull << lane) - 1ull;
    const int dest_lane = wbase[lab] + __builtin_popcountll(mym & lt);

    // copy+cast 16 rows per wave
    #pragma unroll 4
    for (int i = 0; i < 16; ++i) {
        int j = wv * 16 + i;
        int dest = __shfl(dest_lane, j, 64);
        const float4* src = (const float4*)(x + (size_t)(segbase + j) * DIM);
        _Float16* dst = y + (size_t)dest * DIM;
        #pragma unroll
        for (int p = 0; p < 2; ++p) {
            float4 v = src[lane + p * 64];
            f16x4 h;
            h[0] = (_Float16)v.x; h[1] = (_Float16)v.y;
            h[2] = (_Float16)v.z; h[3] = (_Float16)v.w;
            *(f16x4*)(dst + (lane + p * 64) * 4) = h;
        }
    }

    if (tid < 64) denomS[segbase + tid] = 0.f;

    // block 0: tile table + nTiles (it already holds the histogram)
    if (seg == 0) {
        if (tid == 0) *loss = 0.f;
        __shared__ int tb[NCLS + 1];
        if (tid == 0) {
            int t = 0;
            for (int c = 0; c < NCLS; ++c) {
                tb[c] = t;
                int T = (shist[c] + 63) >> 6;
                t += T * (T + 1) / 2;
            }
            tb[NCLS] = t; *nTiles = t;
        }
        __syncthreads();
        const int tot = tb[NCLS];
        for (int t = tid; t < tot; t += 256) {
            int c = 0;
            while (t >= tb[c + 1]) ++c;
            int rem = t - tb[c];
            int T = (shist[c] + 63) >> 6;
            int ti = 0;
            while (rem >= T - ti) { rem -= (T - ti); ++ti; }   // ti<=tj
            int tj = ti + rem;
            tiles[t] = make_int4(soff[c] + ti * 64, soff[c] + tj * 64,
                                 soff[c] + shist[c], 0);
        }
    }
}

// ---------------- 2. gemm + epilogue + pos fold ----------------
// 64x64 tile, BK=128 (4 K-iters), 4 waves each a 32x32 quadrant. LDS
// fragment-ordered [4][4][64][8]; off-diag tiles emit row- AND col-sums
// (S^T reuse); diag tiles stage A only, mask i!=j. NO device fences here.
__global__ __launch_bounds__(256, 5) void gemm_denom_kernel(const _Float16* __restrict__ X,
                                                            const int4* __restrict__ tiles,
                                                            const int* __restrict__ nTiles,
                                                            float* __restrict__ denom,
                                                            const float* __restrict__ o1,
                                                            const float* __restrict__ o2,
                                                            float* __restrict__ loss) {
    __shared__ __align__(16) _Float16 Atile[8192];  // [4][4][64][8] = 16 KiB
    __shared__ __align__(16) _Float16 Btile[8192];
    float* red = (float*)Atile;  // post-loop scratch aliases Atile (LDS stays 32 KiB)

    const int tid  = threadIdx.x;
    const int lane = tid & 63;
    const int wv   = tid >> 6;
    const int lc   = lane & 15;
    const int lq   = lane >> 4;
    const int l8   = lq * 8;
    const int nT   = *nTiles;

    for (int t = blockIdx.x; t < nT; t += gridDim.x) {
        const int4 d = tiles[t];
        const int bm = d.x, bn = d.y, end = d.z;
        const bool diag = (bm == bn);

        f32x4 acc[2][2] = {};

        for (int kb = 0; kb < DIM; kb += 128) {
            __syncthreads();
            #pragma unroll
            for (int g = 0; g < 8; ++g) {
                int grp = wv + g * 4;             // 0..31, wave-uniform
                if (diag && grp >= 16) continue;  // diag: A tile only
                int idx = grp & 15;
                int kk2 = idx >> 2;               // k-chunk of 32
                int rg  = idx & 3;                // row group of 16
                int row = (grp < 16 ? bm : bn) + rg * 16 + lc;
                row = min(row, end - 1);          // partial: dup last row, masked later
                int kcol = kb + kk2 * 32 + l8;
                const _Float16* src = X + (size_t)row * DIM + kcol;
                _Float16* dst = (grp < 16 ? Atile : Btile) + ((kk2 * 4 + rg) * 64 + lane) * 8;
                load16_g2l(dst, src);
            }
            __syncthreads();

            const _Float16* Bbase = diag ? Atile : Btile;
            const int rga = (wv >> 1) * 2;
            const int rgb = (wv & 1) * 2;
            #pragma unroll
            for (int kk2 = 0; kk2 < 4; ++kk2) {
                f16x8 af[2], bf[2];
                #pragma unroll
                for (int q = 0; q < 2; ++q)
                    af[q] = *(const f16x8*)&Atile[((kk2 * 4 + rga + q) * 64 + lane) * 8];
                #pragma unroll
                for (int q = 0; q < 2; ++q)
                    bf[q] = *(const f16x8*)&Bbase[((kk2 * 4 + rgb + q) * 64 + lane) * 8];
                #pragma unroll
                for (int mt = 0; mt < 2; ++mt)
                    #pragma unroll
                    for (int nt = 0; nt < 2; ++nt)
                        acc[mt][nt] = __builtin_amdgcn_mfma_f32_16x16x32_f16(
                            af[mt], bf[nt], acc[mt][nt], 0, 0, 0);
            }
        }

        // epilogue. C/D: col = lane&15, row = (lane>>4)*4 + reg   [m89/m91]
        const int row0 = bm + (wv >> 1) * 32;
        const int col0 = bn + (wv & 1) * 32;
        const float cs = 2.0f * 1.4426950408889634f;  // (1/T)*log2(e)

        float colsum[2] = {0.f, 0.f};
        #pragma unroll
        for (int mt = 0; mt < 2; ++mt) {
            #pragma unroll
            for (int r = 0; r < 4; ++r) {
                int grow = row0 + mt * 16 + lq * 4 + r;
                float s = 0.f;
                #pragma unroll
                for (int nt = 0; nt < 2; ++nt) {
                    int gcol = col0 + nt * 16 + lc;
                    float e = exp2f(acc[mt][nt][r] * cs);
                    bool ok = (gcol < end) && (!diag || (grow != gcol));
                    e = ok ? e : 0.f;
                    s += e;
                    colsum[nt] += e;
                }
                #pragma unroll
                for (int dd = 1; dd < 16; dd <<= 1) s += __shfl_xor(s, dd, 64);
                if (lc == 0 && grow < end) atomicAdd(&denom[grow], s);
            }
        }
        if (!diag) {  // mirrored tile rows (off-diag row blocks are always full)
            #pragma unroll
            for (int nt = 0; nt < 2; ++nt) {
                float c2 = colsum[nt];
                c2 += __shfl_xor(c2, 16, 64);
                c2 += __shfl_xor(c2, 32, 64);
                int gcol = col0 + nt * 16 + lc;
                if (lq == 0 && gcol < end) atomicAdd(&denom[gcol], c2);
            }
        }
    }

    // ---- pos fold on trailing blocks ----
    if (blockIdx.x >= POSB0) {
        __syncthreads();  // tile loop done before Atile reused as red[]
        const int wave = (blockIdx.x - POSB0) * 4 + wv;  // 0..511
        float s = 0.f;
        for (int r = wave; r < 4096; r += 512) {
            const float4* a = (const float4*)(o1 + (size_t)r * DIM);
            const float4* b = (const float4*)(o2 + (size_t)r * DIM);
            float4 va = a[lane], vb = b[lane];
            s += va.x * vb.x + va.y * vb.y + va.z * vb.z + va.w * vb.w;
            va = a[lane + 64]; vb = b[lane + 64];
            s += va.x * vb.x + va.y * vb.y + va.z * vb.z + va.w * vb.w;
        }
        #pragma unroll
        for (int dd = 1; dd < 64; dd <<= 1) s += __shfl_xor(s, dd, 64);
        if (lane == 0) red[wv] = s;
        __syncthreads();
        if (tid == 0)
            atomicAdd(loss, -(red[0] + red[1] + red[2] + red[3]) * (1.0f / 2048.0f));
    }
}

// ---------------- 3. mean(log(denom)) ----------------
__global__ __launch_bounds__(256) void logdenom_kernel(const float* __restrict__ denom,
                                                       float* __restrict__ out) {
    int i = blockIdx.x * 256 + threadIdx.x;
    float v = __logf(denom[i]) * (1.0f / 8192.0f);
    #pragma unroll
    for (int d = 1; d < 64; d <<= 1) v += __shfl_xor(v, d, 64);
    __shared__ float red[4];
    if ((threadIdx.x & 63) == 0) red[threadIdx.x >> 6] = v;
    __syncthreads();
    if (threadIdx.x == 0) atomicAdd(out, red[0] + red[1] + red[2] + red[3]);
}

extern "C" void kernel_launch(void* const* d_in, const int* in_sizes, int n_in,
                              void* d_out, int out_size, void* d_ws, size_t ws_size,
                              hipStream_t stream) {
    const float* out_full = (const float*)d_in[0];  // [8192, 512]
    const float* out_1    = (const float*)d_in[1];  // [4096, 512]
    const float* out_2    = (const float*)d_in[2];  // [4096, 512]
    const int*   labels   = (const int*)d_in[3];    // [8192]
    float* loss = (float*)d_out;

    char* ws = (char*)d_ws;
    _Float16* Xs     = (_Float16*)ws;                 // 8 MiB
    float*    denomS = (float*)(ws + 8388608);        // 32 KiB
    int*      nTiles = (int*)(ws + 8421376);          // 4 B
    int4*     tiles  = (int4*)(ws + 8421504);         // <=33 KiB

    prep_kernel<<<128, 256, 0, stream>>>(out_full, labels, Xs, denomS,
                                         tiles, nTiles, loss);
    gemm_denom_kernel<<<GEMM_GRID, 256, 0, stream>>>(Xs, tiles, nTiles, denomS,
                                                     out_1, out_2, loss);
    logdenom_kernel<<<NROWS / 256, 256, 0, stream>>>(denomS, loss);
}